// Round 11
// baseline (1624.208 us; speedup 1.0000x reference)
//
#include <hip/hip_runtime.h>

#define P_N 100000
#define L_N 20000
#define T_N 8
#define DEG_N 48
#define D_N 64

// ---- workspace layout (float offsets) ----
#define W_PE_W1    0
#define W_PE_B1    64
#define W_PE_W2    128
#define W_PE_B2    4224
#define W_LE_W1    4288
#define W_LE_B1    4352
#define W_LE_W2    4416
#define W_LE_B2    8512
#define W_GRU_WIH  8576
#define W_GRU_WHH  20864
#define W_GRU_BIH  33152
#define W_GRU_BHH  33344
#define W_CELL_WIH 33536
#define W_CELL_WHH 45824
#define W_CELL_BIH 58112
#define W_CELL_BHH 58304
#define W_AM_W1    58496
#define W_AM_B1    91264
#define W_AM_W2    91392
#define W_AM_B2    107776
#define W_AM_W3    107904
#define W_AM_B3    116096
#define OFF_PS     116160                    // path_state fp32 [P,64]
#define OFF_LS     (OFF_PS + P_N*D_N)        // link_state fp32 [L,64]
#define OFF_AG     (OFF_LS + L_N*D_N)        // agg bf16 [L,512]: hi[256] + lo[256]
#define OFF_PSS    (OFF_AG + L_N*4*D_N)      // pss bf16 [P,9,64] at byte 4*OFF_PSS
#define PSS_U32    (P_N*9*D_N/2)
#define OFF_FLAG   (OFF_PSS + PSS_U32)       // dtype flag (int)
#define OFF_WIH16  (OFF_FLAG + 8)            // gru wih bf16 [192][64] (6144 dwords)
#define OFF_WHH16  (OFF_WIH16 + 6144)
#define OFF_LS16   (OFF_WHH16 + 6144)        // link_state bf16 hi [L][64] (640000 dwords)
#define OFF_LW16   (OFF_LS16 + 640000)       // link weights hi[81920]+lo[81920] shorts
#define OFF_LSLO   (OFF_LW16 + 81920)        // link_state bf16 lo [L][64] (640000 dwords)
#define OFF_SORT   (OFF_LSLO + 640000)       // sorted path idx [P] (int)
#define OFF_PLEN   (OFF_SORT + P_N)          // path length [P] (int)
#define OFF_HIST   (OFF_PLEN + P_N)          // hist[0..15] counts, [16..31] base/cursor

typedef __attribute__((ext_vector_type(8))) short bf8_t;
typedef __attribute__((ext_vector_type(4))) float f4_t;
#define MFMA16(a,b,c) __builtin_amdgcn_mfma_f32_16x16x32_bf16(a,b,c,0,0,0)
#define LWLO 81920

__device__ __forceinline__ float bf2f(unsigned short u) {
    return __uint_as_float(((unsigned)u) << 16);
}
__device__ __forceinline__ unsigned short f2bf(float f) {
    unsigned u = __float_as_uint(f);
    unsigned r = u + 0x7FFFu + ((u >> 16) & 1u);
    return (unsigned short)(r >> 16);
}
__device__ __forceinline__ unsigned pk2(float a, float b) {
    return (unsigned)f2bf(a) | ((unsigned)f2bf(b) << 16);
}
// single-instruction hw rcp (v_rcp_f32, <=1 ulp) — avoids ~11-instr IEEE divide
__device__ __forceinline__ float fast_sig(float a) {
    return __builtin_amdgcn_rcpf(1.0f + __expf(-a));
}
// tanh(a) = 2*sigmoid(2a) - 1; inf-safe at both ends
__device__ __forceinline__ float fast_tanh(float a) {
    float s = __builtin_amdgcn_rcpf(1.0f + __expf(-2.0f * a));
    return fmaf(2.0f, s, -1.0f);
}
// barrier that waits ONLY on LDS ops: __syncthreads would drain vmcnt(0),
// stalling every wave on in-flight pss HBM stores / x prefetch loads each
// timestep. sched_barrier(0) stops post-barrier ds_read hoisting (rule 18).
__device__ __forceinline__ void lds_barrier() {
    asm volatile("s_waitcnt lgkmcnt(0)" ::: "memory");
    __builtin_amdgcn_s_barrier();
    __builtin_amdgcn_sched_barrier(0);
}

// ---- dtype detection (+ zero the sort histogram for this launch) ----
__global__ void detect_k(const unsigned short* __restrict__ traffic, int* __restrict__ flag,
                         int* __restrict__ hist) {
    if (threadIdx.x < 32) hist[threadIdx.x] = 0;
    if (threadIdx.x == 0 && blockIdx.x == 0) {
        int plausible = 0;
        for (int i = 0; i < 64; ++i) {
            unsigned short v = traffic[i];
            int ex = (v >> 7) & 0xFF;
            if (!(v & 0x8000) && ex >= 0x6F && ex <= 0x7E) plausible++;
        }
        *flag = (plausible >= 56) ? 1 : 0;
    }
}

// ---- path length + 9-bin histogram ----
__global__ void plen_hist_k(const int* __restrict__ l2p, int* __restrict__ plen,
                            int* __restrict__ hist) {
    int p = blockIdx.x * 256 + threadIdx.x;
    if (p >= P_N) return;
    const int4* r4 = (const int4*)(l2p + (size_t)p * 8);
    int4 a = r4[0], b = r4[1];
    int len = (a.x >= 0) + (a.y >= 0) + (a.z >= 0) + (a.w >= 0)
            + (b.x >= 0) + (b.y >= 0) + (b.z >= 0) + (b.w >= 0);
    plen[p] = len;
    atomicAdd(&hist[len], 1);
}

// ---- exclusive scan of 9 bins -> cursor bases at hist[16..] ----
__global__ void scan_base_k(int* __restrict__ hist) {
    if (threadIdx.x == 0 && blockIdx.x == 0) {
        int base = 0;
        for (int i = 0; i <= T_N; ++i) { int c = hist[i]; hist[16 + i] = base; base += c; }
    }
}

// ---- scatter path ids into length-sorted order (order within bucket arbitrary
// — results are absolute-pid-indexed, so processing order cannot affect output) ----
__global__ void scatter_k(const int* __restrict__ plen, int* __restrict__ hist,
                          int* __restrict__ sorted) {
    int p = blockIdx.x * 256 + threadIdx.x;
    if (p >= P_N) return;
    sorted[atomicAdd(&hist[16 + plen[p]], 1)] = p;
}

// ---- weight -> fp32 conversion ----
struct WSrc { const void* p[22]; };

__global__ void conv_weights_k(WSrc src, float* __restrict__ dst, const int* __restrict__ flag) {
    const int sz[22]  = {64,64,4096,64, 64,64,4096,64, 12288,12288,192,192,
                         12288,12288,192,192, 32768,128,16384,128,8192,64};
    const int off[22] = {0,64,128,4224, 4288,4352,4416,8512, 8576,20864,33152,33344,
                         33536,45824,58112,58304, 58496,91264,91392,107776,107904,116096};
    int a = blockIdx.x;
    float* d = dst + off[a];
    int n = sz[a];
    if (*flag) {
        const unsigned short* s = (const unsigned short*)src.p[a];
        for (int i = threadIdx.x; i < n; i += blockDim.x) d[i] = bf2f(s[i]);
    } else {
        const float* s = (const float*)src.p[a];
        for (int i = threadIdx.x; i < n; i += blockDim.x) d[i] = s[i];
    }
}

// ---- fused GRU + link-side weights fp32 -> bf16 (hi/lo for link side) ----
__global__ void conv_bf16_k(const float* __restrict__ ws,
                            unsigned short* __restrict__ wih, unsigned short* __restrict__ whh,
                            unsigned short* __restrict__ lw) {
    int b = blockIdx.x;
    if (b < 48) {
        int i = b * 256 + threadIdx.x;
        if (i < 12288) { wih[i] = f2bf(ws[W_GRU_WIH + i]); whh[i] = f2bf(ws[W_GRU_WHH + i]); }
    } else {
        int i = (b - 48) * 256 + threadIdx.x;   // 0..81919
        if (i >= 81920) return;
        float v;
        if (i < 32768)      v = ws[W_AM_W1 + i];
        else if (i < 49152) v = ws[W_AM_W2 + (i - 32768)];
        else if (i < 57344) v = ws[W_AM_W3 + (i - 49152)];
        else if (i < 69632) v = ws[W_CELL_WIH + (i - 57344)];
        else                v = ws[W_CELL_WHH + (i - 69632)];
        unsigned short hi = f2bf(v);
        lw[i] = hi;
        lw[LWLO + i] = f2bf(v - bf2f(hi));
    }
}

// ---- scalar-input 2-layer relu MLP embed; optional bf16 hi/lo epilogue ----
__global__ __launch_bounds__(256) void embed_k(
    const void* __restrict__ inp,
    const float* __restrict__ w1, const float* __restrict__ b1,
    const float* __restrict__ w2, const float* __restrict__ b2,
    float* __restrict__ out, unsigned short* __restrict__ ohi,
    unsigned short* __restrict__ olo, int N, const int* __restrict__ flag)
{
    int p = blockIdx.x * 256 + threadIdx.x;
    if (p >= N) return;
    float t = (*flag) ? bf2f(((const unsigned short*)inp)[p]) : ((const float*)inp)[p];
    float h1[64];
#pragma unroll
    for (int k = 0; k < 64; ++k) h1[k] = fmaxf(fmaf(t, w1[k], b1[k]), 0.0f);
#pragma unroll 1
    for (int j = 0; j < 64; ++j) {
        float acc = b2[j];
#pragma unroll
        for (int k = 0; k < 64; ++k) acc = fmaf(h1[k], w2[j * 64 + k], acc);
        float v = fmaxf(acc, 0.0f);
        out[p * 64 + j] = v;
        if (ohi) {                       // link-state call: emit bf16 hi/lo too
            unsigned short hi = f2bf(v);
            ohi[p * 64 + j] = hi;
            olo[p * 64 + j] = f2bf(v - bf2f(hi));
        }
    }
}

// ---- MFMA path GRU: 32 same-length paths/block via sorted index, 4 waves ----
// R4 structure (best measured) + LENGTH-SORTED scheduling: blocks take 32
// paths of (near-)uniform length from `sorted` and bound the t-loop at the
// block max length (prefix-contiguous masks -> OR of masks gives max length).
// Iter 0 (first=1) runs all 8 steps to lay down the static-zero pss rows;
// iters 1-3 run tmax steps (E[len]=5 -> ~5/8 the loop work). Per-path math
// is absolute-pid-indexed and order-independent -> bit-identical output.
__global__ __launch_bounds__(256, 3) void path_gru_mfma_k(
    const unsigned short* __restrict__ wih16,   // [192][64] bf16
    const unsigned short* __restrict__ whh16,
    const float* __restrict__ bih, const float* __restrict__ bhh,
    const unsigned short* __restrict__ ls16,    // [L][64] bf16
    float* __restrict__ path_state,
    const int* __restrict__ l2p, unsigned short* __restrict__ pss,
    const int* __restrict__ sorted, int first)
{
    __shared__ __align__(16) unsigned short xt[2][32 * 72];
    __shared__ __align__(16) unsigned short ht[2][32 * 72];
    __shared__ int lint[32][8];
    __shared__ int lmaskA[32];
    __shared__ int spid[32];

    const int tid = threadIdx.x;
    const int w = tid >> 6;          // wave = dim-slice
    const int L = tid & 63;
    const int col = L & 15;
    const int quad = L >> 4;
    const int p0 = blockIdx.x * 32;
    const int gpath = tid >> 4;      // block-wide gather role: path 0..15 (+16 second round)
    const int gseg = tid & 15;       // 8-byte segment 0..15

    // stage sorted pids + l2p rows + validity masks
    if (tid < 32) {
        int pid = sorted[p0 + tid];
        spid[tid] = pid;
        const int4* r4 = (const int4*)(l2p + (size_t)pid * 8);
        int4 a = r4[0], b = r4[1];
        lint[tid][0] = a.x; lint[tid][1] = a.y; lint[tid][2] = a.z; lint[tid][3] = a.w;
        lint[tid][4] = b.x; lint[tid][5] = b.y; lint[tid][6] = b.z; lint[tid][7] = b.w;
        lmaskA[tid] = (a.x >= 0) | ((a.y >= 0) << 1) | ((a.z >= 0) << 2) | ((a.w >= 0) << 3)
                    | ((b.x >= 0) << 4) | ((b.y >= 0) << 5) | ((b.z >= 0) << 6) | ((b.w >= 0) << 7);
    }

    // weight B-frags for slice w: r-tile w, z-tile 4+w, n-tile 8+w
    bf8_t BIr[2], BHr[2], BIz[2], BHz[2], BIn[2], BHn[2];
#pragma unroll
    for (int f = 0; f < 2; ++f) {
        int orr = ((w) * 16 + col) * 64 + f * 32 + quad * 8;
        int oz  = ((4 + w) * 16 + col) * 64 + f * 32 + quad * 8;
        int on  = ((8 + w) * 16 + col) * 64 + f * 32 + quad * 8;
        BIr[f] = *(const bf8_t*)(wih16 + orr);  BHr[f] = *(const bf8_t*)(whh16 + orr);
        BIz[f] = *(const bf8_t*)(wih16 + oz);   BHz[f] = *(const bf8_t*)(whh16 + oz);
        BIn[f] = *(const bf8_t*)(wih16 + on);   BHn[f] = *(const bf8_t*)(whh16 + on);
    }
    const float bR  = bih[w * 16 + col] + bhh[w * 16 + col];
    const float bZ  = bih[64 + w * 16 + col] + bhh[64 + w * 16 + col];
    const float bIN = bih[128 + w * 16 + col];
    const float bHN = bhh[128 + w * 16 + col];

    lds_barrier();   // spid/lint/lmaskA visible

    // block max length: masks are prefix-contiguous -> OR == (1<<maxlen)-1
    int allm = 0;
#pragma unroll
    for (int i = 0; i < 32; ++i) allm |= lmaskA[i];
    const int tmax = first ? T_N : min(max(32 - __clz(allm), 1), T_N);

    unsigned pm[2][4];
#pragma unroll
    for (int pt = 0; pt < 2; ++pt)
#pragma unroll
        for (int r = 0; r < 4; ++r) pm[pt][r] = (unsigned)lmaskA[pt * 16 + quad * 4 + r];
    const unsigned gm0 = (unsigned)lmaskA[gpath];
    const unsigned gm1 = (unsigned)lmaskA[gpath + 16];
    const int gpid0 = spid[gpath];
    const int gpid1 = spid[gpath + 16];

    // h0 slices (fp32, D-layout) via sorted pid, both path-tiles
    float hf[2][4];
#pragma unroll
    for (int pt = 0; pt < 2; ++pt)
#pragma unroll
        for (int r = 0; r < 4; ++r) {
            hf[pt][r] = path_state[(size_t)spid[pt * 16 + quad * 4 + r] * 64 + w * 16 + col];
            ht[0][(pt * 16 + quad * 4 + r) * 72 + w * 16 + col] = f2bf(hf[pt][r]);
        }

    // gather x0 (both halves)
#pragma unroll
    for (int h2 = 0; h2 < 2; ++h2) {
        const int gp = gpath + h2 * 16;
        int li = lint[gp][0];
        uint2 v; v.x = 0u; v.y = 0u;
        if (li >= 0) v = *(const uint2*)(ls16 + (size_t)li * 64 + gseg * 4);
        *(uint2*)(&xt[0][gp * 72 + gseg * 4]) = v;
    }
    lds_barrier();

#pragma unroll 2
    for (int t = 0; t < tmax; ++t) {
        const int cur = t & 1, nxt = (t + 1) & 1;

        // pss row t stores + x_{t+1} prefetch, both halves.
        // ternary (not bitwise |) — avoids compile-time gm>>-1 poison at t==0
        uint2 pf[2];
#pragma unroll
        for (int h2 = 0; h2 < 2; ++h2) {
            const int gp = gpath + h2 * 16;
            const unsigned gm = h2 ? gm1 : gm0;
            const int gpid = h2 ? gpid1 : gpid0;
            uint2 hv = *(const uint2*)(&ht[cur][gp * 72 + gseg * 4]);
            int keep = (t == 0) ? 1 : (int)((gm >> (t - 1)) & 1);
            if (keep | first) {
                if (!keep) { hv.x = 0u; hv.y = 0u; }
                *(uint2*)(pss + (size_t)gpid * 576 + t * 64 + gseg * 4) = hv;
            }
            pf[h2].x = 0u; pf[h2].y = 0u;
            if (t < tmax - 1) {
                int li = lint[gp][t + 1];
                if (li >= 0) pf[h2] = *(const uint2*)(ls16 + (size_t)li * 64 + gseg * 4);
            }
        }

        // two independent 16-path tiles: 12 MFMAs + gate math each
#pragma unroll
        for (int pt = 0; pt < 2; ++pt) {
            bf8_t xA0 = *(const bf8_t*)(&xt[cur][(pt * 16 + col) * 72 + quad * 8]);
            bf8_t xA1 = *(const bf8_t*)(&xt[cur][(pt * 16 + col) * 72 + 32 + quad * 8]);
            bf8_t hA0 = *(const bf8_t*)(&ht[cur][(pt * 16 + col) * 72 + quad * 8]);
            bf8_t hA1 = *(const bf8_t*)(&ht[cur][(pt * 16 + col) * 72 + 32 + quad * 8]);

            f4_t aR = {bR, bR, bR, bR};
            f4_t aZ = {bZ, bZ, bZ, bZ};
            f4_t aI = {bIN, bIN, bIN, bIN};
            f4_t aH = {bHN, bHN, bHN, bHN};
            aR = MFMA16(xA0, BIr[0], aR); aR = MFMA16(xA1, BIr[1], aR);
            aR = MFMA16(hA0, BHr[0], aR); aR = MFMA16(hA1, BHr[1], aR);
            aZ = MFMA16(xA0, BIz[0], aZ); aZ = MFMA16(xA1, BIz[1], aZ);
            aZ = MFMA16(hA0, BHz[0], aZ); aZ = MFMA16(hA1, BHz[1], aZ);
            aI = MFMA16(xA0, BIn[0], aI); aI = MFMA16(xA1, BIn[1], aI);
            aH = MFMA16(hA0, BHn[0], aH); aH = MFMA16(hA1, BHn[1], aH);

            // gate math: 4 values/lane per tile
#pragma unroll
            for (int r = 0; r < 4; ++r) {
                float rr = fast_sig(aR[r]);
                float zz = fast_sig(aZ[r]);
                float nn = fast_tanh(fmaf(rr, aH[r], aI[r]));
                float hb = hf[pt][r];
                float hv = fmaf(zz, hb - nn, nn);     // (1-z)n + z h
                hf[pt][r] = ((pm[pt][r] >> t) & 1) ? hv : hb;
            }
#pragma unroll
            for (int r = 0; r < 4; ++r)
                ht[nxt][(pt * 16 + quad * 4 + r) * 72 + w * 16 + col] = f2bf(hf[pt][r]);
        }

        if (t < tmax - 1) {
#pragma unroll
            for (int h2 = 0; h2 < 2; ++h2)
                *(uint2*)(&xt[nxt][(gpath + h2 * 16) * 72 + gseg * 4]) = pf[h2];
        }
        lds_barrier();
    }

    // epilogue: h_tmax lives in ht[tmax&1]; pss row tmax masked by valid(tmax-1).
    // Shorter paths in the block already stored their row `len` during the loop
    // (keep=valid(len-1)); rows beyond stay at iter-0 zeros.
    const int fin = tmax & 1;
#pragma unroll
    for (int h2 = 0; h2 < 2; ++h2) {
        const int gp = gpath + h2 * 16;
        const unsigned gm = h2 ? gm1 : gm0;
        const int gpid = h2 ? gpid1 : gpid0;
        uint2 hv = *(const uint2*)(&ht[fin][gp * 72 + gseg * 4]);
        int keep = (int)((gm >> (tmax - 1)) & 1);
        if (keep | first) {
            if (!keep) { hv.x = 0u; hv.y = 0u; }
            *(uint2*)(pss + (size_t)gpid * 576 + tmax * 64 + gseg * 4) = hv;
        }
    }
#pragma unroll
    for (int pt = 0; pt < 2; ++pt)
#pragma unroll
        for (int r = 0; r < 4; ++r)
            path_state[(size_t)spid[pt * 16 + quad * 4 + r] * 64 + w * 16 + col] = hf[pt][r];
}

// ---- link aggregation (R4 config — measured best): 4 links/block, 1 wave
// each, branch-free fully-unrolled gather, readfirstlane-scalarized p2l. ----
__global__ __launch_bounds__(256, 4) void link_agg_k(
    const int* __restrict__ p2l, const unsigned short* __restrict__ pss,
    unsigned short* __restrict__ agg16)
{
    const int lane = threadIdx.x & 63;
    const int l = __builtin_amdgcn_readfirstlane(blockIdx.x * 4 + (threadIdx.x >> 6));
    const int* __restrict__ row = p2l + (size_t)l * 96;

    float vmin = INFINITY, vmax = -INFINITY, vsum = 0.0f;
    int cnt = 0;
#pragma unroll
    for (int d = 0; d < DEG_N; ++d) {
        int pid = row[d * 2];
        int pos = row[d * 2 + 1];
        size_t off = (size_t)max(pid, 0) * 576 + (size_t)pos * 64 + lane;
        float v = bf2f(pss[off]);
        bool ok = pid >= 0;
        vmin = fminf(vmin, ok ? v : INFINITY);
        vmax = fmaxf(vmax, ok ? v : -INFINITY);
        vsum += ok ? v : 0.0f;
        cnt += ok ? 1 : 0;
    }
    float mean = vsum / (float)max(cnt, 1);

    unsigned short* rw = agg16 + (size_t)l * 512;
    float vals[4] = {vmin, vmax, vsum, mean};
#pragma unroll
    for (int c = 0; c < 4; ++c) {
        unsigned short hi = f2bf(vals[c]);
        rw[c * 64 + lane] = hi;
        rw[256 + c * 64 + lane] = f2bf(vals[c] - bf2f(hi));
    }
}

// ---- MFMA link update (R4 config — measured best), hi/lo compensated:
// MLP(256->128->128->64) + GRU cell. 1 wave per block (16 links), grid 1250. ----
__global__ __launch_bounds__(64, 2) void link_upd_mfma_k(
    const unsigned short* __restrict__ lw,
    const float* __restrict__ b1, const float* __restrict__ b2, const float* __restrict__ b3,
    const float* __restrict__ cbih, const float* __restrict__ cbhh,
    const unsigned short* __restrict__ agg16,
    float* __restrict__ link_state,
    unsigned short* __restrict__ lshi, unsigned short* __restrict__ lslo)
{
    __shared__ __align__(16) unsigned short tile[2 * 16 * 136];
    const int L = threadIdx.x & 63;
    const int col = L & 15;
    const int quad = L >> 4;
    const int l0 = blockIdx.x * 16;
    const int mlink = min(l0 + col, L_N - 1);
    unsigned short* tlhi = &tile[0];
    unsigned short* tllo = &tile[16 * 136];

    const unsigned short* w1b = lw;            // [128][256]
    const unsigned short* w2b = lw + 32768;    // [128][128]
    const unsigned short* w3b = lw + 49152;    // [64][128]
    const unsigned short* cih = lw + 57344;    // [192][64]
    const unsigned short* chh = lw + 69632;    // [192][64]

    // phase 1
    {
        bf8_t Ah[8], Al[8];
#pragma unroll
        for (int f = 0; f < 8; ++f) {
            Ah[f] = *(const bf8_t*)(agg16 + (size_t)mlink * 512 + f * 32 + quad * 8);
            Al[f] = *(const bf8_t*)(agg16 + (size_t)mlink * 512 + 256 + f * 32 + quad * 8);
        }
#pragma unroll
        for (int nt = 0; nt < 8; ++nt) {
            float bb = b1[nt * 16 + col];
            f4_t acc = {bb, bb, bb, bb};
#pragma unroll
            for (int f = 0; f < 8; ++f) {
                size_t o = (size_t)(nt * 16 + col) * 256 + f * 32 + quad * 8;
                bf8_t Bh = *(const bf8_t*)(w1b + o);
                bf8_t Bl = *(const bf8_t*)(w1b + LWLO + o);
                acc = MFMA16(Ah[f], Bh, acc);
                acc = MFMA16(Ah[f], Bl, acc);
                acc = MFMA16(Al[f], Bh, acc);
            }
#pragma unroll
            for (int r = 0; r < 4; ++r) {
                float v = fmaxf(acc[r], 0.0f);
                unsigned short hi = f2bf(v);
                tlhi[(quad * 4 + r) * 136 + nt * 16 + col] = hi;
                tllo[(quad * 4 + r) * 136 + nt * 16 + col] = f2bf(v - bf2f(hi));
            }
        }
    }
    // phase 2
    {
        bf8_t Ah[4], Al[4];
#pragma unroll
        for (int f = 0; f < 4; ++f) {
            Ah[f] = *(const bf8_t*)(tlhi + col * 136 + f * 32 + quad * 8);
            Al[f] = *(const bf8_t*)(tllo + col * 136 + f * 32 + quad * 8);
        }
        float vv[8][4];
#pragma unroll
        for (int nt = 0; nt < 8; ++nt) {
            float bb = b2[nt * 16 + col];
            f4_t acc = {bb, bb, bb, bb};
#pragma unroll
            for (int f = 0; f < 4; ++f) {
                size_t o = (size_t)(nt * 16 + col) * 128 + f * 32 + quad * 8;
                bf8_t Bh = *(const bf8_t*)(w2b + o);
                bf8_t Bl = *(const bf8_t*)(w2b + LWLO + o);
                acc = MFMA16(Ah[f], Bh, acc);
                acc = MFMA16(Ah[f], Bl, acc);
                acc = MFMA16(Al[f], Bh, acc);
            }
#pragma unroll
            for (int r = 0; r < 4; ++r) vv[nt][r] = fmaxf(acc[r], 0.0f);
        }
#pragma unroll
        for (int nt = 0; nt < 8; ++nt)
#pragma unroll
            for (int r = 0; r < 4; ++r) {
                unsigned short hi = f2bf(vv[nt][r]);
                tlhi[(quad * 4 + r) * 136 + nt * 16 + col] = hi;
                tllo[(quad * 4 + r) * 136 + nt * 16 + col] = f2bf(vv[nt][r] - bf2f(hi));
            }
    }
    // phase 3
    {
        bf8_t Ah[4], Al[4];
#pragma unroll
        for (int f = 0; f < 4; ++f) {
            Ah[f] = *(const bf8_t*)(tlhi + col * 136 + f * 32 + quad * 8);
            Al[f] = *(const bf8_t*)(tllo + col * 136 + f * 32 + quad * 8);
        }
        float vv[4][4];
#pragma unroll
        for (int nt = 0; nt < 4; ++nt) {
            float bb = b3[nt * 16 + col];
            f4_t acc = {bb, bb, bb, bb};
#pragma unroll
            for (int f = 0; f < 4; ++f) {
                size_t o = (size_t)(nt * 16 + col) * 128 + f * 32 + quad * 8;
                bf8_t Bh = *(const bf8_t*)(w3b + o);
                bf8_t Bl = *(const bf8_t*)(w3b + LWLO + o);
                acc = MFMA16(Ah[f], Bh, acc);
                acc = MFMA16(Ah[f], Bl, acc);
                acc = MFMA16(Al[f], Bh, acc);
            }
#pragma unroll
            for (int r = 0; r < 4; ++r) vv[nt][r] = fmaxf(acc[r], 0.0f);
        }
#pragma unroll
        for (int nt = 0; nt < 4; ++nt)
#pragma unroll
            for (int r = 0; r < 4; ++r) {
                unsigned short hi = f2bf(vv[nt][r]);
                tlhi[(quad * 4 + r) * 136 + nt * 16 + col] = hi;
                tllo[(quad * 4 + r) * 136 + nt * 16 + col] = f2bf(vv[nt][r] - bf2f(hi));
            }
    }
    // GRU cell
    bf8_t xAh[2], xAl[2], hAh[2], hAl[2];
#pragma unroll
    for (int f = 0; f < 2; ++f) {
        xAh[f] = *(const bf8_t*)(tlhi + col * 136 + f * 32 + quad * 8);
        xAl[f] = *(const bf8_t*)(tllo + col * 136 + f * 32 + quad * 8);
        hAh[f] = *(const bf8_t*)(lshi + (size_t)mlink * 64 + f * 32 + quad * 8);
        hAl[f] = *(const bf8_t*)(lslo + (size_t)mlink * 64 + f * 32 + quad * 8);
    }
    float hf[16];
#pragma unroll
    for (int nt = 0; nt < 4; ++nt)
#pragma unroll
        for (int r = 0; r < 4; ++r) {
            int ml = min(l0 + quad * 4 + r, L_N - 1);
            hf[nt * 4 + r] = link_state[(size_t)ml * 64 + nt * 16 + col];
        }
    f4_t aRZ[8], aIN[4], aHN[4];
#pragma unroll
    for (int nt = 0; nt < 8; ++nt) {
        float bb = cbih[nt * 16 + col] + cbhh[nt * 16 + col];
        aRZ[nt][0] = bb; aRZ[nt][1] = bb; aRZ[nt][2] = bb; aRZ[nt][3] = bb;
    }
#pragma unroll
    for (int nt = 0; nt < 4; ++nt) {
        float bi = cbih[128 + nt * 16 + col], bh = cbhh[128 + nt * 16 + col];
        aIN[nt][0] = bi; aIN[nt][1] = bi; aIN[nt][2] = bi; aIN[nt][3] = bi;
        aHN[nt][0] = bh; aHN[nt][1] = bh; aHN[nt][2] = bh; aHN[nt][3] = bh;
    }
#pragma unroll
    for (int nt = 0; nt < 8; ++nt) {
#pragma unroll
        for (int f = 0; f < 2; ++f) {
            size_t o = (size_t)(nt * 16 + col) * 64 + f * 32 + quad * 8;
            bf8_t Bih = *(const bf8_t*)(cih + o);
            bf8_t Bil = *(const bf8_t*)(cih + LWLO + o);
            bf8_t Bhh = *(const bf8_t*)(chh + o);
            bf8_t Bhl = *(const bf8_t*)(chh + LWLO + o);
            aRZ[nt] = MFMA16(xAh[f], Bih, aRZ[nt]);
            aRZ[nt] = MFMA16(xAh[f], Bil, aRZ[nt]);
            aRZ[nt] = MFMA16(xAl[f], Bih, aRZ[nt]);
            aRZ[nt] = MFMA16(hAh[f], Bhh, aRZ[nt]);
            aRZ[nt] = MFMA16(hAh[f], Bhl, aRZ[nt]);
            aRZ[nt] = MFMA16(hAl[f], Bhh, aRZ[nt]);
        }
    }
#pragma unroll
    for (int nt = 0; nt < 4; ++nt) {
#pragma unroll
        for (int f = 0; f < 2; ++f) {
            size_t o = (size_t)((8 + nt) * 16 + col) * 64 + f * 32 + quad * 8;
            bf8_t Bih = *(const bf8_t*)(cih + o);
            bf8_t Bil = *(const bf8_t*)(cih + LWLO + o);
            bf8_t Bhh = *(const bf8_t*)(chh + o);
            bf8_t Bhl = *(const bf8_t*)(chh + LWLO + o);
            aIN[nt] = MFMA16(xAh[f], Bih, aIN[nt]);
            aIN[nt] = MFMA16(xAh[f], Bil, aIN[nt]);
            aIN[nt] = MFMA16(xAl[f], Bih, aIN[nt]);
            aHN[nt] = MFMA16(hAh[f], Bhh, aHN[nt]);
            aHN[nt] = MFMA16(hAh[f], Bhl, aHN[nt]);
            aHN[nt] = MFMA16(hAl[f], Bhh, aHN[nt]);
        }
    }
#pragma unroll
    for (int nt = 0; nt < 4; ++nt)
#pragma unroll
        for (int r = 0; r < 4; ++r) {
            int mrow = l0 + quad * 4 + r;
            float rr = fast_sig(aRZ[nt][r]);
            float zz = fast_sig(aRZ[nt + 4][r]);
            float nn = fast_tanh(fmaf(rr, aHN[nt][r], aIN[nt][r]));
            float hb = hf[nt * 4 + r];
            float hv = fmaf(zz, hb - nn, nn);
            if (mrow < L_N) {
                link_state[(size_t)mrow * 64 + nt * 16 + col] = hv;
                unsigned short hi = f2bf(hv);
                lshi[(size_t)mrow * 64 + nt * 16 + col] = hi;
                lslo[(size_t)mrow * 64 + nt * 16 + col] = f2bf(hv - bf2f(hi));
            }
        }
}

// ---- final fp32 -> (bf16 | f32) output ----
__global__ void final_out_k(const float* __restrict__ ps, const float* __restrict__ ls,
                            void* __restrict__ out, const int* __restrict__ flag)
{
    int i = blockIdx.x * 256 + threadIdx.x;
    int e = i * 2;
    float a, b;
    if (e < P_N * D_N) { a = ps[e]; b = ps[e + 1]; }
    else               { a = ls[e - P_N * D_N]; b = ls[e - P_N * D_N + 1]; }
    if (*flag) {
        ((unsigned*)out)[i] = pk2(a, b);
    } else {
        float2 v; v.x = a; v.y = b;
        ((float2*)out)[i] = v;
    }
}

extern "C" void kernel_launch(void* const* d_in, const int* in_sizes, int n_in,
                              void* d_out, int out_size, void* d_ws, size_t ws_size,
                              hipStream_t stream)
{
    const int* l2p = (const int*)d_in[2];
    const int* p2l = (const int*)d_in[3];
    float* ws = (float*)d_ws;
    int* flag = (int*)(ws + OFF_FLAG);
    unsigned short* wih16 = (unsigned short*)(ws + OFF_WIH16);
    unsigned short* whh16 = (unsigned short*)(ws + OFF_WHH16);
    unsigned short* lshi  = (unsigned short*)(ws + OFF_LS16);
    unsigned short* lslo  = (unsigned short*)(ws + OFF_LSLO);
    unsigned short* lw16  = (unsigned short*)(ws + OFF_LW16);
    unsigned short* agg16 = (unsigned short*)(ws + OFF_AG);
    unsigned short* pss   = (unsigned short*)(ws + OFF_PSS);
    int* sorted = (int*)(ws + OFF_SORT);
    int* plen   = (int*)(ws + OFF_PLEN);
    int* hist   = (int*)(ws + OFF_HIST);

    detect_k<<<1, 64, 0, stream>>>((const unsigned short*)d_in[0], flag, hist);

    WSrc srcs;
    for (int i = 0; i < 22; ++i) srcs.p[i] = d_in[4 + i];
    conv_weights_k<<<22, 256, 0, stream>>>(srcs, ws, flag);
    conv_bf16_k<<<368, 256, 0, stream>>>(ws, wih16, whh16, lw16);

    // length-sort the paths (one-time; order within bucket arbitrary)
    plen_hist_k<<<(P_N + 255) / 256, 256, 0, stream>>>(l2p, plen, hist);
    scan_base_k<<<1, 64, 0, stream>>>(hist);
    scatter_k<<<(P_N + 255) / 256, 256, 0, stream>>>(plen, hist, sorted);

    embed_k<<<(P_N + 255) / 256, 256, 0, stream>>>(d_in[0], ws + W_PE_W1, ws + W_PE_B1,
                                                   ws + W_PE_W2, ws + W_PE_B2, ws + OFF_PS,
                                                   (unsigned short*)nullptr, (unsigned short*)nullptr,
                                                   P_N, flag);
    embed_k<<<(L_N + 255) / 256, 256, 0, stream>>>(d_in[1], ws + W_LE_W1, ws + W_LE_B1,
                                                   ws + W_LE_W2, ws + W_LE_B2, ws + OFF_LS,
                                                   lshi, lslo, L_N, flag);

    for (int it = 0; it < 4; ++it) {
        path_gru_mfma_k<<<P_N / 32, 256, 0, stream>>>(
            wih16, whh16, ws + W_GRU_BIH, ws + W_GRU_BHH,
            lshi, ws + OFF_PS, l2p, pss, sorted, it == 0 ? 1 : 0);
        link_agg_k<<<L_N / 4, 256, 0, stream>>>(p2l, pss, agg16);
        link_upd_mfma_k<<<L_N / 16, 64, 0, stream>>>(
            lw16, ws + W_AM_B1, ws + W_AM_B2, ws + W_AM_B3,
            ws + W_CELL_BIH, ws + W_CELL_BHH,
            agg16, ws + OFF_LS, lshi, lslo);
    }
    final_out_k<<<(P_N * D_N + L_N * D_N) / 512, 256, 0, stream>>>(
        ws + OFF_PS, ws + OFF_LS, d_out, flag);
}

// Round 12
// 857.672 us; speedup vs baseline: 1.8937x; 1.8937x over previous
//
#include <hip/hip_runtime.h>

#define P_N 100000
#define L_N 20000
#define T_N 8
#define DEG_N 48
#define D_N 64

// ---- workspace layout (float offsets) ----
#define W_PE_W1    0
#define W_PE_B1    64
#define W_PE_W2    128
#define W_PE_B2    4224
#define W_LE_W1    4288
#define W_LE_B1    4352
#define W_LE_W2    4416
#define W_LE_B2    8512
#define W_GRU_WIH  8576
#define W_GRU_WHH  20864
#define W_GRU_BIH  33152
#define W_GRU_BHH  33344
#define W_CELL_WIH 33536
#define W_CELL_WHH 45824
#define W_CELL_BIH 58112
#define W_CELL_BHH 58304
#define W_AM_W1    58496
#define W_AM_B1    91264
#define W_AM_W2    91392
#define W_AM_B2    107776
#define W_AM_W3    107904
#define W_AM_B3    116096
#define OFF_PS     116160                    // path_state fp32 [P,64]
#define OFF_LS     (OFF_PS + P_N*D_N)        // link_state fp32 [L,64]
#define OFF_AG     (OFF_LS + L_N*D_N)        // agg bf16 [L,512]: hi[256] + lo[256]
#define OFF_PSS    (OFF_AG + L_N*4*D_N)      // pss bf16 [P,9,64] at byte 4*OFF_PSS
#define PSS_U32    (P_N*9*D_N/2)
#define OFF_FLAG   (OFF_PSS + PSS_U32)       // dtype flag (int)
#define OFF_WIH16  (OFF_FLAG + 8)            // gru wih bf16 [192][64] (6144 dwords)
#define OFF_WHH16  (OFF_WIH16 + 6144)
#define OFF_LS16   (OFF_WHH16 + 6144)        // link_state bf16 hi [L][64] (640000 dwords)
#define OFF_LW16   (OFF_LS16 + 640000)       // link weights hi[81920]+lo[81920] shorts
#define OFF_LSLO   (OFF_LW16 + 81920)        // link_state bf16 lo [L][64] (640000 dwords)
#define OFF_SORT   (OFF_LSLO + 640000)       // sorted path idx [P] (int)
#define OFF_PLEN   (OFF_SORT + P_N)          // path length [P] (int)
#define OFF_HIST   (OFF_PLEN + P_N)          // hist[0..15] counts, [16..31] base/cursor

typedef __attribute__((ext_vector_type(8))) short bf8_t;
typedef __attribute__((ext_vector_type(4))) float f4_t;
#define MFMA16(a,b,c) __builtin_amdgcn_mfma_f32_16x16x32_bf16(a,b,c,0,0,0)
#define LWLO 81920

__device__ __forceinline__ float bf2f(unsigned short u) {
    return __uint_as_float(((unsigned)u) << 16);
}
__device__ __forceinline__ unsigned short f2bf(float f) {
    unsigned u = __float_as_uint(f);
    unsigned r = u + 0x7FFFu + ((u >> 16) & 1u);
    return (unsigned short)(r >> 16);
}
__device__ __forceinline__ unsigned pk2(float a, float b) {
    return (unsigned)f2bf(a) | ((unsigned)f2bf(b) << 16);
}
// single-instruction hw rcp (v_rcp_f32, <=1 ulp) — avoids ~11-instr IEEE divide
__device__ __forceinline__ float fast_sig(float a) {
    return __builtin_amdgcn_rcpf(1.0f + __expf(-a));
}
// tanh(a) = 2*sigmoid(2a) - 1; inf-safe at both ends
__device__ __forceinline__ float fast_tanh(float a) {
    float s = __builtin_amdgcn_rcpf(1.0f + __expf(-2.0f * a));
    return fmaf(2.0f, s, -1.0f);
}
// barrier that waits ONLY on LDS ops: __syncthreads would drain vmcnt(0),
// stalling every wave on in-flight pss HBM stores / x prefetch loads each
// timestep. sched_barrier(0) stops post-barrier ds_read hoisting (rule 18).
__device__ __forceinline__ void lds_barrier() {
    asm volatile("s_waitcnt lgkmcnt(0)" ::: "memory");
    __builtin_amdgcn_s_barrier();
    __builtin_amdgcn_sched_barrier(0);
}

// ---- dtype detection (+ zero the sort histogram for this launch) ----
__global__ void detect_k(const unsigned short* __restrict__ traffic, int* __restrict__ flag,
                         int* __restrict__ hist) {
    if (threadIdx.x < 32) hist[threadIdx.x] = 0;
    if (threadIdx.x == 0 && blockIdx.x == 0) {
        int plausible = 0;
        for (int i = 0; i < 64; ++i) {
            unsigned short v = traffic[i];
            int ex = (v >> 7) & 0xFF;
            if (!(v & 0x8000) && ex >= 0x6F && ex <= 0x7E) plausible++;
        }
        *flag = (plausible >= 56) ? 1 : 0;
    }
}

// ---- path length + 9-bin histogram.
// R11 ERRATA: 100k atomicAdds onto 9 GLOBAL addresses serialized -> 389us.
// Fix (Guideline 12): per-block LDS histogram, then <=9 global atomics/block
// (391 blocks x 9 = 3.5k global atomics total). ----
__global__ void plen_hist_k(const int* __restrict__ l2p, int* __restrict__ plen,
                            int* __restrict__ hist) {
    __shared__ int lh[16];
    const int tid = threadIdx.x;
    if (tid < 16) lh[tid] = 0;
    __syncthreads();
    int p = blockIdx.x * 256 + tid;
    if (p < P_N) {
        const int4* r4 = (const int4*)(l2p + (size_t)p * 8);
        int4 a = r4[0], b = r4[1];
        int len = (a.x >= 0) + (a.y >= 0) + (a.z >= 0) + (a.w >= 0)
                + (b.x >= 0) + (b.y >= 0) + (b.z >= 0) + (b.w >= 0);
        plen[p] = len;
        atomicAdd(&lh[len], 1);          // LDS atomic: intra-block only
    }
    __syncthreads();
    if (tid <= T_N && lh[tid]) atomicAdd(&hist[tid], lh[tid]);
}

// ---- exclusive scan of 9 bins -> cursor bases at hist[16..] ----
__global__ void scan_base_k(int* __restrict__ hist) {
    if (threadIdx.x == 0 && blockIdx.x == 0) {
        int base = 0;
        for (int i = 0; i <= T_N; ++i) { int c = hist[i]; hist[16 + i] = base; base += c; }
    }
}

// ---- scatter path ids into length-sorted order.
// R11 ERRATA: per-thread global cursor atomics (100k on 9 addresses) ~345us.
// Fix: block builds LDS histogram + local offsets, reserves a contiguous
// range per bin with ONE global atomicAdd per bin, then writes
// sorted[base + local_off]. Order within bucket arbitrary — results are
// absolute-pid-indexed, so processing order cannot affect output. ----
__global__ void scatter_k(const int* __restrict__ plen, int* __restrict__ hist,
                          int* __restrict__ sorted) {
    __shared__ int lh[16];
    __shared__ int lbase[16];
    const int tid = threadIdx.x;
    if (tid < 16) lh[tid] = 0;
    __syncthreads();
    int p = blockIdx.x * 256 + tid;
    int len = 0, loff = 0;
    if (p < P_N) {
        len = plen[p];
        loff = atomicAdd(&lh[len], 1);   // LDS atomic: local offset within block's bin
    }
    __syncthreads();
    if (tid <= T_N && lh[tid]) lbase[tid] = atomicAdd(&hist[16 + tid], lh[tid]);
    __syncthreads();
    if (p < P_N) sorted[lbase[len] + loff] = p;
}

// ---- weight -> fp32 conversion ----
struct WSrc { const void* p[22]; };

__global__ void conv_weights_k(WSrc src, float* __restrict__ dst, const int* __restrict__ flag) {
    const int sz[22]  = {64,64,4096,64, 64,64,4096,64, 12288,12288,192,192,
                         12288,12288,192,192, 32768,128,16384,128,8192,64};
    const int off[22] = {0,64,128,4224, 4288,4352,4416,8512, 8576,20864,33152,33344,
                         33536,45824,58112,58304, 58496,91264,91392,107776,107904,116096};
    int a = blockIdx.x;
    float* d = dst + off[a];
    int n = sz[a];
    if (*flag) {
        const unsigned short* s = (const unsigned short*)src.p[a];
        for (int i = threadIdx.x; i < n; i += blockDim.x) d[i] = bf2f(s[i]);
    } else {
        const float* s = (const float*)src.p[a];
        for (int i = threadIdx.x; i < n; i += blockDim.x) d[i] = s[i];
    }
}

// ---- fused GRU + link-side weights fp32 -> bf16 (hi/lo for link side) ----
__global__ void conv_bf16_k(const float* __restrict__ ws,
                            unsigned short* __restrict__ wih, unsigned short* __restrict__ whh,
                            unsigned short* __restrict__ lw) {
    int b = blockIdx.x;
    if (b < 48) {
        int i = b * 256 + threadIdx.x;
        if (i < 12288) { wih[i] = f2bf(ws[W_GRU_WIH + i]); whh[i] = f2bf(ws[W_GRU_WHH + i]); }
    } else {
        int i = (b - 48) * 256 + threadIdx.x;   // 0..81919
        if (i >= 81920) return;
        float v;
        if (i < 32768)      v = ws[W_AM_W1 + i];
        else if (i < 49152) v = ws[W_AM_W2 + (i - 32768)];
        else if (i < 57344) v = ws[W_AM_W3 + (i - 49152)];
        else if (i < 69632) v = ws[W_CELL_WIH + (i - 57344)];
        else                v = ws[W_CELL_WHH + (i - 69632)];
        unsigned short hi = f2bf(v);
        lw[i] = hi;
        lw[LWLO + i] = f2bf(v - bf2f(hi));
    }
}

// ---- scalar-input 2-layer relu MLP embed; optional bf16 hi/lo epilogue ----
__global__ __launch_bounds__(256) void embed_k(
    const void* __restrict__ inp,
    const float* __restrict__ w1, const float* __restrict__ b1,
    const float* __restrict__ w2, const float* __restrict__ b2,
    float* __restrict__ out, unsigned short* __restrict__ ohi,
    unsigned short* __restrict__ olo, int N, const int* __restrict__ flag)
{
    int p = blockIdx.x * 256 + threadIdx.x;
    if (p >= N) return;
    float t = (*flag) ? bf2f(((const unsigned short*)inp)[p]) : ((const float*)inp)[p];
    float h1[64];
#pragma unroll
    for (int k = 0; k < 64; ++k) h1[k] = fmaxf(fmaf(t, w1[k], b1[k]), 0.0f);
#pragma unroll 1
    for (int j = 0; j < 64; ++j) {
        float acc = b2[j];
#pragma unroll
        for (int k = 0; k < 64; ++k) acc = fmaf(h1[k], w2[j * 64 + k], acc);
        float v = fmaxf(acc, 0.0f);
        out[p * 64 + j] = v;
        if (ohi) {                       // link-state call: emit bf16 hi/lo too
            unsigned short hi = f2bf(v);
            ohi[p * 64 + j] = hi;
            olo[p * 64 + j] = f2bf(v - bf2f(hi));
        }
    }
}

// ---- MFMA path GRU: 32 same-length paths/block via sorted index, 4 waves ----
// R4 structure (best measured) + LENGTH-SORTED scheduling: blocks take 32
// paths of (near-)uniform length from `sorted` and bound the t-loop at the
// block max length (prefix-contiguous masks -> OR of masks gives max length).
// Iter 0 (first=1) runs all 8 steps to lay down the static-zero pss rows;
// iters 1-3 run tmax steps (E[len]=5 -> ~5/8 the loop work). Per-path math
// is absolute-pid-indexed and order-independent -> bit-identical output.
__global__ __launch_bounds__(256, 3) void path_gru_mfma_k(
    const unsigned short* __restrict__ wih16,   // [192][64] bf16
    const unsigned short* __restrict__ whh16,
    const float* __restrict__ bih, const float* __restrict__ bhh,
    const unsigned short* __restrict__ ls16,    // [L][64] bf16
    float* __restrict__ path_state,
    const int* __restrict__ l2p, unsigned short* __restrict__ pss,
    const int* __restrict__ sorted, int first)
{
    __shared__ __align__(16) unsigned short xt[2][32 * 72];
    __shared__ __align__(16) unsigned short ht[2][32 * 72];
    __shared__ int lint[32][8];
    __shared__ int lmaskA[32];
    __shared__ int spid[32];

    const int tid = threadIdx.x;
    const int w = tid >> 6;          // wave = dim-slice
    const int L = tid & 63;
    const int col = L & 15;
    const int quad = L >> 4;
    const int p0 = blockIdx.x * 32;
    const int gpath = tid >> 4;      // block-wide gather role: path 0..15 (+16 second round)
    const int gseg = tid & 15;       // 8-byte segment 0..15

    // stage sorted pids + l2p rows + validity masks
    if (tid < 32) {
        int pid = sorted[p0 + tid];
        spid[tid] = pid;
        const int4* r4 = (const int4*)(l2p + (size_t)pid * 8);
        int4 a = r4[0], b = r4[1];
        lint[tid][0] = a.x; lint[tid][1] = a.y; lint[tid][2] = a.z; lint[tid][3] = a.w;
        lint[tid][4] = b.x; lint[tid][5] = b.y; lint[tid][6] = b.z; lint[tid][7] = b.w;
        lmaskA[tid] = (a.x >= 0) | ((a.y >= 0) << 1) | ((a.z >= 0) << 2) | ((a.w >= 0) << 3)
                    | ((b.x >= 0) << 4) | ((b.y >= 0) << 5) | ((b.z >= 0) << 6) | ((b.w >= 0) << 7);
    }

    // weight B-frags for slice w: r-tile w, z-tile 4+w, n-tile 8+w
    bf8_t BIr[2], BHr[2], BIz[2], BHz[2], BIn[2], BHn[2];
#pragma unroll
    for (int f = 0; f < 2; ++f) {
        int orr = ((w) * 16 + col) * 64 + f * 32 + quad * 8;
        int oz  = ((4 + w) * 16 + col) * 64 + f * 32 + quad * 8;
        int on  = ((8 + w) * 16 + col) * 64 + f * 32 + quad * 8;
        BIr[f] = *(const bf8_t*)(wih16 + orr);  BHr[f] = *(const bf8_t*)(whh16 + orr);
        BIz[f] = *(const bf8_t*)(wih16 + oz);   BHz[f] = *(const bf8_t*)(whh16 + oz);
        BIn[f] = *(const bf8_t*)(wih16 + on);   BHn[f] = *(const bf8_t*)(whh16 + on);
    }
    const float bR  = bih[w * 16 + col] + bhh[w * 16 + col];
    const float bZ  = bih[64 + w * 16 + col] + bhh[64 + w * 16 + col];
    const float bIN = bih[128 + w * 16 + col];
    const float bHN = bhh[128 + w * 16 + col];

    lds_barrier();   // spid/lint/lmaskA visible

    // block max length: masks are prefix-contiguous -> OR == (1<<maxlen)-1
    int allm = 0;
#pragma unroll
    for (int i = 0; i < 32; ++i) allm |= lmaskA[i];
    const int tmax = first ? T_N : min(max(32 - __clz(allm), 1), T_N);

    unsigned pm[2][4];
#pragma unroll
    for (int pt = 0; pt < 2; ++pt)
#pragma unroll
        for (int r = 0; r < 4; ++r) pm[pt][r] = (unsigned)lmaskA[pt * 16 + quad * 4 + r];
    const unsigned gm0 = (unsigned)lmaskA[gpath];
    const unsigned gm1 = (unsigned)lmaskA[gpath + 16];
    const int gpid0 = spid[gpath];
    const int gpid1 = spid[gpath + 16];

    // h0 slices (fp32, D-layout) via sorted pid, both path-tiles
    float hf[2][4];
#pragma unroll
    for (int pt = 0; pt < 2; ++pt)
#pragma unroll
        for (int r = 0; r < 4; ++r) {
            hf[pt][r] = path_state[(size_t)spid[pt * 16 + quad * 4 + r] * 64 + w * 16 + col];
            ht[0][(pt * 16 + quad * 4 + r) * 72 + w * 16 + col] = f2bf(hf[pt][r]);
        }

    // gather x0 (both halves)
#pragma unroll
    for (int h2 = 0; h2 < 2; ++h2) {
        const int gp = gpath + h2 * 16;
        int li = lint[gp][0];
        uint2 v; v.x = 0u; v.y = 0u;
        if (li >= 0) v = *(const uint2*)(ls16 + (size_t)li * 64 + gseg * 4);
        *(uint2*)(&xt[0][gp * 72 + gseg * 4]) = v;
    }
    lds_barrier();

#pragma unroll 2
    for (int t = 0; t < tmax; ++t) {
        const int cur = t & 1, nxt = (t + 1) & 1;

        // pss row t stores + x_{t+1} prefetch, both halves.
        // ternary (not bitwise |) — avoids compile-time gm>>-1 poison at t==0
        uint2 pf[2];
#pragma unroll
        for (int h2 = 0; h2 < 2; ++h2) {
            const int gp = gpath + h2 * 16;
            const unsigned gm = h2 ? gm1 : gm0;
            const int gpid = h2 ? gpid1 : gpid0;
            uint2 hv = *(const uint2*)(&ht[cur][gp * 72 + gseg * 4]);
            int keep = (t == 0) ? 1 : (int)((gm >> (t - 1)) & 1);
            if (keep | first) {
                if (!keep) { hv.x = 0u; hv.y = 0u; }
                *(uint2*)(pss + (size_t)gpid * 576 + t * 64 + gseg * 4) = hv;
            }
            pf[h2].x = 0u; pf[h2].y = 0u;
            if (t < tmax - 1) {
                int li = lint[gp][t + 1];
                if (li >= 0) pf[h2] = *(const uint2*)(ls16 + (size_t)li * 64 + gseg * 4);
            }
        }

        // two independent 16-path tiles: 12 MFMAs + gate math each
#pragma unroll
        for (int pt = 0; pt < 2; ++pt) {
            bf8_t xA0 = *(const bf8_t*)(&xt[cur][(pt * 16 + col) * 72 + quad * 8]);
            bf8_t xA1 = *(const bf8_t*)(&xt[cur][(pt * 16 + col) * 72 + 32 + quad * 8]);
            bf8_t hA0 = *(const bf8_t*)(&ht[cur][(pt * 16 + col) * 72 + quad * 8]);
            bf8_t hA1 = *(const bf8_t*)(&ht[cur][(pt * 16 + col) * 72 + 32 + quad * 8]);

            f4_t aR = {bR, bR, bR, bR};
            f4_t aZ = {bZ, bZ, bZ, bZ};
            f4_t aI = {bIN, bIN, bIN, bIN};
            f4_t aH = {bHN, bHN, bHN, bHN};
            aR = MFMA16(xA0, BIr[0], aR); aR = MFMA16(xA1, BIr[1], aR);
            aR = MFMA16(hA0, BHr[0], aR); aR = MFMA16(hA1, BHr[1], aR);
            aZ = MFMA16(xA0, BIz[0], aZ); aZ = MFMA16(xA1, BIz[1], aZ);
            aZ = MFMA16(hA0, BHz[0], aZ); aZ = MFMA16(hA1, BHz[1], aZ);
            aI = MFMA16(xA0, BIn[0], aI); aI = MFMA16(xA1, BIn[1], aI);
            aH = MFMA16(hA0, BHn[0], aH); aH = MFMA16(hA1, BHn[1], aH);

            // gate math: 4 values/lane per tile
#pragma unroll
            for (int r = 0; r < 4; ++r) {
                float rr = fast_sig(aR[r]);
                float zz = fast_sig(aZ[r]);
                float nn = fast_tanh(fmaf(rr, aH[r], aI[r]));
                float hb = hf[pt][r];
                float hv = fmaf(zz, hb - nn, nn);     // (1-z)n + z h
                hf[pt][r] = ((pm[pt][r] >> t) & 1) ? hv : hb;
            }
#pragma unroll
            for (int r = 0; r < 4; ++r)
                ht[nxt][(pt * 16 + quad * 4 + r) * 72 + w * 16 + col] = f2bf(hf[pt][r]);
        }

        if (t < tmax - 1) {
#pragma unroll
            for (int h2 = 0; h2 < 2; ++h2)
                *(uint2*)(&xt[nxt][(gpath + h2 * 16) * 72 + gseg * 4]) = pf[h2];
        }
        lds_barrier();
    }

    // epilogue: h_tmax lives in ht[tmax&1]; pss row tmax masked by valid(tmax-1).
    // Shorter paths in the block already stored their row `len` during the loop
    // (keep=valid(len-1)); rows beyond stay at iter-0 zeros.
    const int fin = tmax & 1;
#pragma unroll
    for (int h2 = 0; h2 < 2; ++h2) {
        const int gp = gpath + h2 * 16;
        const unsigned gm = h2 ? gm1 : gm0;
        const int gpid = h2 ? gpid1 : gpid0;
        uint2 hv = *(const uint2*)(&ht[fin][gp * 72 + gseg * 4]);
        int keep = (int)((gm >> (tmax - 1)) & 1);
        if (keep | first) {
            if (!keep) { hv.x = 0u; hv.y = 0u; }
            *(uint2*)(pss + (size_t)gpid * 576 + tmax * 64 + gseg * 4) = hv;
        }
    }
#pragma unroll
    for (int pt = 0; pt < 2; ++pt)
#pragma unroll
        for (int r = 0; r < 4; ++r)
            path_state[(size_t)spid[pt * 16 + quad * 4 + r] * 64 + w * 16 + col] = hf[pt][r];
}

// ---- link aggregation (R4 config — measured best): 4 links/block, 1 wave
// each, branch-free fully-unrolled gather, readfirstlane-scalarized p2l. ----
__global__ __launch_bounds__(256, 4) void link_agg_k(
    const int* __restrict__ p2l, const unsigned short* __restrict__ pss,
    unsigned short* __restrict__ agg16)
{
    const int lane = threadIdx.x & 63;
    const int l = __builtin_amdgcn_readfirstlane(blockIdx.x * 4 + (threadIdx.x >> 6));
    const int* __restrict__ row = p2l + (size_t)l * 96;

    float vmin = INFINITY, vmax = -INFINITY, vsum = 0.0f;
    int cnt = 0;
#pragma unroll
    for (int d = 0; d < DEG_N; ++d) {
        int pid = row[d * 2];
        int pos = row[d * 2 + 1];
        size_t off = (size_t)max(pid, 0) * 576 + (size_t)pos * 64 + lane;
        float v = bf2f(pss[off]);
        bool ok = pid >= 0;
        vmin = fminf(vmin, ok ? v : INFINITY);
        vmax = fmaxf(vmax, ok ? v : -INFINITY);
        vsum += ok ? v : 0.0f;
        cnt += ok ? 1 : 0;
    }
    float mean = vsum / (float)max(cnt, 1);

    unsigned short* rw = agg16 + (size_t)l * 512;
    float vals[4] = {vmin, vmax, vsum, mean};
#pragma unroll
    for (int c = 0; c < 4; ++c) {
        unsigned short hi = f2bf(vals[c]);
        rw[c * 64 + lane] = hi;
        rw[256 + c * 64 + lane] = f2bf(vals[c] - bf2f(hi));
    }
}

// ---- MFMA link update (R4 config — measured best), hi/lo compensated:
// MLP(256->128->128->64) + GRU cell. 1 wave per block (16 links), grid 1250. ----
__global__ __launch_bounds__(64, 2) void link_upd_mfma_k(
    const unsigned short* __restrict__ lw,
    const float* __restrict__ b1, const float* __restrict__ b2, const float* __restrict__ b3,
    const float* __restrict__ cbih, const float* __restrict__ cbhh,
    const unsigned short* __restrict__ agg16,
    float* __restrict__ link_state,
    unsigned short* __restrict__ lshi, unsigned short* __restrict__ lslo)
{
    __shared__ __align__(16) unsigned short tile[2 * 16 * 136];
    const int L = threadIdx.x & 63;
    const int col = L & 15;
    const int quad = L >> 4;
    const int l0 = blockIdx.x * 16;
    const int mlink = min(l0 + col, L_N - 1);
    unsigned short* tlhi = &tile[0];
    unsigned short* tllo = &tile[16 * 136];

    const unsigned short* w1b = lw;            // [128][256]
    const unsigned short* w2b = lw + 32768;    // [128][128]
    const unsigned short* w3b = lw + 49152;    // [64][128]
    const unsigned short* cih = lw + 57344;    // [192][64]
    const unsigned short* chh = lw + 69632;    // [192][64]

    // phase 1
    {
        bf8_t Ah[8], Al[8];
#pragma unroll
        for (int f = 0; f < 8; ++f) {
            Ah[f] = *(const bf8_t*)(agg16 + (size_t)mlink * 512 + f * 32 + quad * 8);
            Al[f] = *(const bf8_t*)(agg16 + (size_t)mlink * 512 + 256 + f * 32 + quad * 8);
        }
#pragma unroll
        for (int nt = 0; nt < 8; ++nt) {
            float bb = b1[nt * 16 + col];
            f4_t acc = {bb, bb, bb, bb};
#pragma unroll
            for (int f = 0; f < 8; ++f) {
                size_t o = (size_t)(nt * 16 + col) * 256 + f * 32 + quad * 8;
                bf8_t Bh = *(const bf8_t*)(w1b + o);
                bf8_t Bl = *(const bf8_t*)(w1b + LWLO + o);
                acc = MFMA16(Ah[f], Bh, acc);
                acc = MFMA16(Ah[f], Bl, acc);
                acc = MFMA16(Al[f], Bh, acc);
            }
#pragma unroll
            for (int r = 0; r < 4; ++r) {
                float v = fmaxf(acc[r], 0.0f);
                unsigned short hi = f2bf(v);
                tlhi[(quad * 4 + r) * 136 + nt * 16 + col] = hi;
                tllo[(quad * 4 + r) * 136 + nt * 16 + col] = f2bf(v - bf2f(hi));
            }
        }
    }
    // phase 2
    {
        bf8_t Ah[4], Al[4];
#pragma unroll
        for (int f = 0; f < 4; ++f) {
            Ah[f] = *(const bf8_t*)(tlhi + col * 136 + f * 32 + quad * 8);
            Al[f] = *(const bf8_t*)(tllo + col * 136 + f * 32 + quad * 8);
        }
        float vv[8][4];
#pragma unroll
        for (int nt = 0; nt < 8; ++nt) {
            float bb = b2[nt * 16 + col];
            f4_t acc = {bb, bb, bb, bb};
#pragma unroll
            for (int f = 0; f < 4; ++f) {
                size_t o = (size_t)(nt * 16 + col) * 128 + f * 32 + quad * 8;
                bf8_t Bh = *(const bf8_t*)(w2b + o);
                bf8_t Bl = *(const bf8_t*)(w2b + LWLO + o);
                acc = MFMA16(Ah[f], Bh, acc);
                acc = MFMA16(Ah[f], Bl, acc);
                acc = MFMA16(Al[f], Bh, acc);
            }
#pragma unroll
            for (int r = 0; r < 4; ++r) vv[nt][r] = fmaxf(acc[r], 0.0f);
        }
#pragma unroll
        for (int nt = 0; nt < 8; ++nt)
#pragma unroll
            for (int r = 0; r < 4; ++r) {
                unsigned short hi = f2bf(vv[nt][r]);
                tlhi[(quad * 4 + r) * 136 + nt * 16 + col] = hi;
                tllo[(quad * 4 + r) * 136 + nt * 16 + col] = f2bf(vv[nt][r] - bf2f(hi));
            }
    }
    // phase 3
    {
        bf8_t Ah[4], Al[4];
#pragma unroll
        for (int f = 0; f < 4; ++f) {
            Ah[f] = *(const bf8_t*)(tlhi + col * 136 + f * 32 + quad * 8);
            Al[f] = *(const bf8_t*)(tllo + col * 136 + f * 32 + quad * 8);
        }
        float vv[4][4];
#pragma unroll
        for (int nt = 0; nt < 4; ++nt) {
            float bb = b3[nt * 16 + col];
            f4_t acc = {bb, bb, bb, bb};
#pragma unroll
            for (int f = 0; f < 4; ++f) {
                size_t o = (size_t)(nt * 16 + col) * 128 + f * 32 + quad * 8;
                bf8_t Bh = *(const bf8_t*)(w3b + o);
                bf8_t Bl = *(const bf8_t*)(w3b + LWLO + o);
                acc = MFMA16(Ah[f], Bh, acc);
                acc = MFMA16(Ah[f], Bl, acc);
                acc = MFMA16(Al[f], Bh, acc);
            }
#pragma unroll
            for (int r = 0; r < 4; ++r) vv[nt][r] = fmaxf(acc[r], 0.0f);
        }
#pragma unroll
        for (int nt = 0; nt < 4; ++nt)
#pragma unroll
            for (int r = 0; r < 4; ++r) {
                unsigned short hi = f2bf(vv[nt][r]);
                tlhi[(quad * 4 + r) * 136 + nt * 16 + col] = hi;
                tllo[(quad * 4 + r) * 136 + nt * 16 + col] = f2bf(vv[nt][r] - bf2f(hi));
            }
    }
    // GRU cell
    bf8_t xAh[2], xAl[2], hAh[2], hAl[2];
#pragma unroll
    for (int f = 0; f < 2; ++f) {
        xAh[f] = *(const bf8_t*)(tlhi + col * 136 + f * 32 + quad * 8);
        xAl[f] = *(const bf8_t*)(tllo + col * 136 + f * 32 + quad * 8);
        hAh[f] = *(const bf8_t*)(lshi + (size_t)mlink * 64 + f * 32 + quad * 8);
        hAl[f] = *(const bf8_t*)(lslo + (size_t)mlink * 64 + f * 32 + quad * 8);
    }
    float hf[16];
#pragma unroll
    for (int nt = 0; nt < 4; ++nt)
#pragma unroll
        for (int r = 0; r < 4; ++r) {
            int ml = min(l0 + quad * 4 + r, L_N - 1);
            hf[nt * 4 + r] = link_state[(size_t)ml * 64 + nt * 16 + col];
        }
    f4_t aRZ[8], aIN[4], aHN[4];
#pragma unroll
    for (int nt = 0; nt < 8; ++nt) {
        float bb = cbih[nt * 16 + col] + cbhh[nt * 16 + col];
        aRZ[nt][0] = bb; aRZ[nt][1] = bb; aRZ[nt][2] = bb; aRZ[nt][3] = bb;
    }
#pragma unroll
    for (int nt = 0; nt < 4; ++nt) {
        float bi = cbih[128 + nt * 16 + col], bh = cbhh[128 + nt * 16 + col];
        aIN[nt][0] = bi; aIN[nt][1] = bi; aIN[nt][2] = bi; aIN[nt][3] = bi;
        aHN[nt][0] = bh; aHN[nt][1] = bh; aHN[nt][2] = bh; aHN[nt][3] = bh;
    }
#pragma unroll
    for (int nt = 0; nt < 8; ++nt) {
#pragma unroll
        for (int f = 0; f < 2; ++f) {
            size_t o = (size_t)(nt * 16 + col) * 64 + f * 32 + quad * 8;
            bf8_t Bih = *(const bf8_t*)(cih + o);
            bf8_t Bil = *(const bf8_t*)(cih + LWLO + o);
            bf8_t Bhh = *(const bf8_t*)(chh + o);
            bf8_t Bhl = *(const bf8_t*)(chh + LWLO + o);
            aRZ[nt] = MFMA16(xAh[f], Bih, aRZ[nt]);
            aRZ[nt] = MFMA16(xAh[f], Bil, aRZ[nt]);
            aRZ[nt] = MFMA16(xAl[f], Bih, aRZ[nt]);
            aRZ[nt] = MFMA16(hAh[f], Bhh, aRZ[nt]);
            aRZ[nt] = MFMA16(hAh[f], Bhl, aRZ[nt]);
            aRZ[nt] = MFMA16(hAl[f], Bhh, aRZ[nt]);
        }
    }
#pragma unroll
    for (int nt = 0; nt < 4; ++nt) {
#pragma unroll
        for (int f = 0; f < 2; ++f) {
            size_t o = (size_t)((8 + nt) * 16 + col) * 64 + f * 32 + quad * 8;
            bf8_t Bih = *(const bf8_t*)(cih + o);
            bf8_t Bil = *(const bf8_t*)(cih + LWLO + o);
            bf8_t Bhh = *(const bf8_t*)(chh + o);
            bf8_t Bhl = *(const bf8_t*)(chh + LWLO + o);
            aIN[nt] = MFMA16(xAh[f], Bih, aIN[nt]);
            aIN[nt] = MFMA16(xAh[f], Bil, aIN[nt]);
            aIN[nt] = MFMA16(xAl[f], Bih, aIN[nt]);
            aHN[nt] = MFMA16(hAh[f], Bhh, aHN[nt]);
            aHN[nt] = MFMA16(hAh[f], Bhl, aHN[nt]);
            aHN[nt] = MFMA16(hAl[f], Bhh, aHN[nt]);
        }
    }
#pragma unroll
    for (int nt = 0; nt < 4; ++nt)
#pragma unroll
        for (int r = 0; r < 4; ++r) {
            int mrow = l0 + quad * 4 + r;
            float rr = fast_sig(aRZ[nt][r]);
            float zz = fast_sig(aRZ[nt + 4][r]);
            float nn = fast_tanh(fmaf(rr, aHN[nt][r], aIN[nt][r]));
            float hb = hf[nt * 4 + r];
            float hv = fmaf(zz, hb - nn, nn);
            if (mrow < L_N) {
                link_state[(size_t)mrow * 64 + nt * 16 + col] = hv;
                unsigned short hi = f2bf(hv);
                lshi[(size_t)mrow * 64 + nt * 16 + col] = hi;
                lslo[(size_t)mrow * 64 + nt * 16 + col] = f2bf(hv - bf2f(hi));
            }
        }
}

// ---- final fp32 -> (bf16 | f32) output ----
__global__ void final_out_k(const float* __restrict__ ps, const float* __restrict__ ls,
                            void* __restrict__ out, const int* __restrict__ flag)
{
    int i = blockIdx.x * 256 + threadIdx.x;
    int e = i * 2;
    float a, b;
    if (e < P_N * D_N) { a = ps[e]; b = ps[e + 1]; }
    else               { a = ls[e - P_N * D_N]; b = ls[e - P_N * D_N + 1]; }
    if (*flag) {
        ((unsigned*)out)[i] = pk2(a, b);
    } else {
        float2 v; v.x = a; v.y = b;
        ((float2*)out)[i] = v;
    }
}

extern "C" void kernel_launch(void* const* d_in, const int* in_sizes, int n_in,
                              void* d_out, int out_size, void* d_ws, size_t ws_size,
                              hipStream_t stream)
{
    const int* l2p = (const int*)d_in[2];
    const int* p2l = (const int*)d_in[3];
    float* ws = (float*)d_ws;
    int* flag = (int*)(ws + OFF_FLAG);
    unsigned short* wih16 = (unsigned short*)(ws + OFF_WIH16);
    unsigned short* whh16 = (unsigned short*)(ws + OFF_WHH16);
    unsigned short* lshi  = (unsigned short*)(ws + OFF_LS16);
    unsigned short* lslo  = (unsigned short*)(ws + OFF_LSLO);
    unsigned short* lw16  = (unsigned short*)(ws + OFF_LW16);
    unsigned short* agg16 = (unsigned short*)(ws + OFF_AG);
    unsigned short* pss   = (unsigned short*)(ws + OFF_PSS);
    int* sorted = (int*)(ws + OFF_SORT);
    int* plen   = (int*)(ws + OFF_PLEN);
    int* hist   = (int*)(ws + OFF_HIST);

    detect_k<<<1, 64, 0, stream>>>((const unsigned short*)d_in[0], flag, hist);

    WSrc srcs;
    for (int i = 0; i < 22; ++i) srcs.p[i] = d_in[4 + i];
    conv_weights_k<<<22, 256, 0, stream>>>(srcs, ws, flag);
    conv_bf16_k<<<368, 256, 0, stream>>>(ws, wih16, whh16, lw16);

    // length-sort the paths (one-time; order within bucket arbitrary)
    plen_hist_k<<<(P_N + 255) / 256, 256, 0, stream>>>(l2p, plen, hist);
    scan_base_k<<<1, 64, 0, stream>>>(hist);
    scatter_k<<<(P_N + 255) / 256, 256, 0, stream>>>(plen, hist, sorted);

    embed_k<<<(P_N + 255) / 256, 256, 0, stream>>>(d_in[0], ws + W_PE_W1, ws + W_PE_B1,
                                                   ws + W_PE_W2, ws + W_PE_B2, ws + OFF_PS,
                                                   (unsigned short*)nullptr, (unsigned short*)nullptr,
                                                   P_N, flag);
    embed_k<<<(L_N + 255) / 256, 256, 0, stream>>>(d_in[1], ws + W_LE_W1, ws + W_LE_B1,
                                                   ws + W_LE_W2, ws + W_LE_B2, ws + OFF_LS,
                                                   lshi, lslo, L_N, flag);

    for (int it = 0; it < 4; ++it) {
        path_gru_mfma_k<<<P_N / 32, 256, 0, stream>>>(
            wih16, whh16, ws + W_GRU_BIH, ws + W_GRU_BHH,
            lshi, ws + OFF_PS, l2p, pss, sorted, it == 0 ? 1 : 0);
        link_agg_k<<<L_N / 4, 256, 0, stream>>>(p2l, pss, agg16);
        link_upd_mfma_k<<<L_N / 16, 64, 0, stream>>>(
            lw16, ws + W_AM_B1, ws + W_AM_B2, ws + W_AM_B3,
            ws + W_CELL_BIH, ws + W_CELL_BHH,
            agg16, ws + OFF_LS, lshi, lslo);
    }
    final_out_k<<<(P_N * D_N + L_N * D_N) / 512, 256, 0, stream>>>(
        ws + OFF_PS, ws + OFF_LS, d_out, flag);
}